// Round 15
// baseline (1602.337 us; speedup 1.0000x reference)
//
#include <hip/hip_runtime.h>

#define LLEN 128
#define BB 4
#define DD 768
#define HH 300
#define G5 1500
#define H3 900
#define NTT 7
#define NRR 12
#define NCHB 10
#define RPB 150
#define OPB 30

// ---- fp32 workspace layout (ws as float*) ----
#define C_WIH  0
#define C_X    1152000
#define F_BIH  2265216
#define F_BTR  2266720
#define F_PRE  2267040
// PRE region reused after k_scan5:
#define F_HG0  (F_PRE)
#define F_HG1  (F_PRE+153600)
#define F_A0   (F_PRE+307200)
#define F_E0   (F_PRE+460800)
#define F_GF0  (F_PRE+616832)
#define F_GF1  (F_PRE+618048)
// beyond PRE:
#define F_HNER (F_PRE+768000)
#define F_HRE  (F_HNER+153600)
#define F_HSH  (F_HRE+153600)
// A1/E1 live in the DEAD Wih region (only read by k_pre2, which runs before k_globfeat)
#define F_A1   0
#define F_E1   153600
#define F_AUX  (F_HSH+153600)
// aux per-batch (AUXB floats): gb[0,1500) cb[1504,1804) hb[1808,2108) sums[2112,2128)
#define AUXB   2432
#define AUX_FL 9728
#define WS_NEED_BYTES ((size_t)(F_AUX+10752)*4)

typedef unsigned short u16;
typedef unsigned int u32;

__device__ __forceinline__ float bf2f(u16 u) {
  union { u32 i; float f; } v; v.i = ((u32)u) << 16; return v.f;
}
__device__ __forceinline__ u16 f2bf(float f) {
  union { float f; u32 i; } v; v.f = f;
  u32 r = v.i + 0x7fffu + ((v.i >> 16) & 1u);
  return (u16)(r >> 16);
}
__device__ __forceinline__ float ldin(const void* p, int i, bool f32) {
  return f32 ? ((const float*)p)[i] : bf2f(((const u16*)p)[i]);
}
__device__ __forceinline__ bool is32(const void* mk) {
  return ((const u16*)mk)[0] == 0;  // fp32 1.0 low half = 0x0000; bf16 1.0 = 0x3F80
}
__device__ __forceinline__ float wsum(float x) {
  #pragma unroll
  for (int d = 1; d < 64; d <<= 1) x += __shfl_xor(x, d);
  return x;
}
// coherent (agent-scope, sc1) handoff accessors
__device__ __forceinline__ float aload(const float* p) {
  int v = __hip_atomic_load((const int*)p, __ATOMIC_RELAXED, __HIP_MEMORY_SCOPE_AGENT);
  union { int i; float f; } u; u.i = v; return u.f;
}
__device__ __forceinline__ void astore(float* p, float v) {
  union { float f; int i; } u; u.f = v;
  __hip_atomic_store((int*)p, u.i, __ATOMIC_RELAXED, __HIP_MEMORY_SCOPE_AGENT);
}
// lean inter-block barrier (R12/R13/R14-proven)
__device__ __forceinline__ void gbar(int* flag, int tid, int target) {
  __syncthreads();
  if (tid == 0) {
    __builtin_amdgcn_s_waitcnt(0);
    __hip_atomic_fetch_add(flag, 1, __ATOMIC_RELAXED, __HIP_MEMORY_SCOPE_AGENT);
    while (__hip_atomic_load(flag, __ATOMIC_RELAXED, __HIP_MEMORY_SCOPE_AGENT) < target)
      __builtin_amdgcn_s_sleep(1);
  }
  __syncthreads();
}

// ---- bf16-path canon of x / Wih to fp32 (fp32 path: early exit) ----
__global__ void k_canon2(const void* xo, const void* mk, const void* Wih, float* ws) {
  if (is32(mk)) return;
  int piece = blockIdx.y;
  int i = blockIdx.x * 256 + threadIdx.x;
  if (piece == 0) { if (i < 1152000) ws[C_WIH + i] = bf2f(((const u16*)Wih)[i]); }
  else            { if (i < 393216)  ws[C_X + i]   = bf2f(((const u16*)xo)[i]); }
}

// ---- biases + flag zero ----
__global__ void k_misc(const void* bih, const void* bhh, const void* btr, const void* mk, float* ws) {
  bool f32 = is32(mk);
  int i = blockIdx.x * 256 + threadIdx.x;
  if (i < 1504) ws[F_BIH + i] = (i < G5) ? ldin(bih, i, f32) + ldin(bhh, i, f32) : 0.f;
  else if (i < 1824) { int j = i - 1504; ws[F_BTR + j] = (j < HH) ? ldin(btr, j, f32) : 0.f; }
  else if (i >= 2048 && i < 3072) ((int*)(ws + F_AUX + AUX_FL))[i - 2048] = 0;
}

// ---- pre = x @ W_ih^T + (b_ih + b_hh); 8 lb-rows x 750-out tile per block ----
__global__ void k_pre2(const void* xo, const void* Wo, const void* mk,
                       const float* cX, const float* cW, const float* biasf, float* pre) {
  bool f32 = is32(mk);
  const float* X = f32 ? (const float*)xo : cX;
  const float* W = f32 ? (const float*)Wo : cW;
  __shared__ __align__(16) float xl[8 * DD];
  int tid = threadIdx.x;
  int lb0 = (blockIdx.x >> 1) * 8;
  int half = blockIdx.x & 1;
  for (int e = tid; e < 8 * DD; e += 256) xl[e] = X[(size_t)lb0 * DD + e];
  __syncthreads();
  for (int j = half * 750 + tid; j < half * 750 + 750; j += 256) {
    const float4* w = (const float4*)(W + (size_t)j * DD);
    float acc[8] = {0.f, 0.f, 0.f, 0.f, 0.f, 0.f, 0.f, 0.f};
    #pragma unroll 2
    for (int k = 0; k < DD / 4; ++k) {
      float4 u = w[k];
      #pragma unroll
      for (int r = 0; r < 8; ++r) {
        const float4 p = *(const float4*)(xl + r * DD + k * 4);
        acc[r] += u.x * p.x + u.y * p.y + u.z * p.z + u.w * p.w;
      }
    }
    float bias = biasf[j];
    #pragma unroll
    for (int r = 0; r < 8; ++r) pre[(size_t)(lb0 + r) * G5 + j] = acc[r] + bias;
  }
}

// ---- scan: 10 chunk-blocks x 4 batches; register weights direct from input; wave cumsum ----
__global__ void __launch_bounds__(512, 2) k_scan5(const float* pre, const void* Whh, const void* Wtr,
                                                  const void* mk, const float* btrf,
                                                  float* hner, float* hre, float* hsh, float* aux) {
  __shared__ __align__(16) float h_l[304];
  __shared__ __align__(16) float ci_l[304];
  __shared__ __align__(16) float ga_l[1504];
  __shared__ __align__(16) float cat_l[904];
  __shared__ __align__(16) float ps[512];
  __shared__ float exv[160];
  __shared__ float pp[40];
  __shared__ float sums_l[8];
  bool f32 = is32(mk);
  int b = blockIdx.x / NCHB, ch = blockIdx.x % NCHB;
  int s = ch >> 1;
  int r0 = ch * RPB;
  int tid = threadIdx.x;
  float* gb   = aux + b * AUXB;
  float* cb   = gb + 1504;
  float* hb   = gb + 1808;
  float* sums = gb + 2112;
  int* flags = (int*)(aux + AUX_FL) + b * 256;
  for (int i = tid; i < 304; i += 512) { h_l[i] = 0.f; ci_l[i] = 0.f; }
  __syncthreads();
  int j = tid / RPB, r = tid - j * RPB;   // GEMV1: 3-way K split, tid<450
  int o2 = tid % OPB, jj = tid / OPB;     // GEMV2: 16-way K split, tid<480
  int kb = j * 100;

  // ---- preload loop-invariant weight slices into registers, direct from inputs ----
  float2 wh[50];
  if (tid < 450) {
    if (f32) {
      const float2* wp = (const float2*)((const float*)Whh + (size_t)(r0 + r) * HH + kb);
      #pragma unroll
      for (int kk = 0; kk < 50; ++kk) wh[kk] = wp[kk];
    } else {
      const u16* wp = (const u16*)Whh + (size_t)(r0 + r) * HH + kb;
      #pragma unroll
      for (int kk = 0; kk < 50; ++kk) { wh[kk].x = bf2f(wp[2 * kk]); wh[kk].y = bf2f(wp[2 * kk + 1]); }
    }
  }
  float2 wt[29];
  int k2b = jj * 29;
  int k2e = (k2b + 29 < 450) ? (k2b + 29) : 450;
  int nk2 = k2e - k2b;
  if (tid < 480) {
    int out = ch * OPB + o2;
    if (f32) {
      const float2* wp = (const float2*)((const float*)Wtr + (size_t)out * H3 + 2 * k2b);
      #pragma unroll
      for (int q = 0; q < 29; ++q) if (q < nk2) wt[q] = wp[q];
    } else {
      const u16* wp = (const u16*)Wtr + (size_t)out * H3 + 2 * k2b;
      #pragma unroll
      for (int q = 0; q < 29; ++q) if (q < nk2) { wt[q].x = bf2f(wp[2 * q]); wt[q].y = bf2f(wp[2 * q + 1]); }
    }
  }

  for (int t = 0; t < LLEN; ++t) {
    // ---- phase 1: gate slice ----
    if (t > 0) {
      for (int i = tid; i < HH; i += 512) { h_l[i] = aload(hb + i); ci_l[i] = aload(cb + i); }
      __syncthreads();
    }
    if (tid < 450) {
      float acc = (j == 0) ? pre[((size_t)t * BB + b) * G5 + r0 + r] : 0.f;
      if (t > 0) {
        #pragma unroll
        for (int kk = 0; kk < 50; ++kk)
          acc += wh[kk].x * h_l[kb + 2 * kk] + wh[kk].y * h_l[kb + 2 * kk + 1];
      }
      ps[tid] = acc;
    }
    __syncthreads();
    if (tid < RPB) {
      float g = ps[tid] + ps[RPB + tid] + ps[2 * RPB + tid];
      if (s == 0) astore(gb + r0 + tid, tanhf(g));
      else exv[tid] = __expf(g);
    }
    __syncthreads();
    if (s > 0) {
      if (tid < 30) {
        int base = tid * 5;
        pp[tid] = ((exv[base] + exv[base+1]) + (exv[base+2] + exv[base+3])) + exv[base+4];
      }
      __syncthreads();
      // wave-0 Hillis-Steele exclusive scan over 30 partials (replaces serial tid0 scan)
      if (tid < 64) {
        float v = (tid < 30) ? pp[tid] : 0.f;
        float inc = v;
        #pragma unroll
        for (int d = 1; d < 32; d <<= 1) { float t2 = __shfl_up(inc, d); if (tid >= d) inc += t2; }
        if (tid < 30) pp[tid] = inc - v;
        if (tid == 29) astore(sums + (ch - 2), inc);   // this half's exp total
      }
      __syncthreads();
      if (tid < 30) {
        int base = tid * 5;
        float run = pp[tid];
        run += exv[base];     astore(gb + r0 + base,     run);
        run += exv[base + 1]; astore(gb + r0 + base + 1, run);
        run += exv[base + 2]; astore(gb + r0 + base + 2, run);
        run += exv[base + 3]; astore(gb + r0 + base + 3, run);
        run += exv[base + 4]; astore(gb + r0 + base + 4, run);  // raw local-inclusive cumsum
      }
    }
    gbar(flags + 2 * t, tid, NCHB);
    // ---- phase 2: combine (redundant) + GEMV2 slice ----
    for (int i = tid; i < G5; i += 512) ga_l[i] = aload(gb + i);
    if (tid < 8) sums_l[tid] = aload(sums + tid);
    __syncthreads();
    if (tid < HH) {
      float c = ga_l[tid];
      float v[4];
      #pragma unroll
      for (int s1 = 0; s1 < 4; ++s1) {
        float raw = ga_l[(s1 + 1) * HH + tid];
        float off = (tid >= RPB) ? sums_l[2 * s1] : 0.f;
        float S = sums_l[2 * s1] + sums_l[2 * s1 + 1];
        v[s1] = (raw + off) / S;
      }
      float eg_cin = 1.f - v[0], rg_cin = v[1], eg_c = 1.f - v[2], rg_c = v[3];
      float ci = (t > 0) ? ci_l[tid] : 0.f;
      float ov_c = rg_c * eg_c;
      float up_c = rg_c - ov_c, dn_c = eg_c - ov_c;
      float ov_i = rg_cin * eg_cin;
      float up_i = rg_cin - ov_i, dn_i = eg_cin - ov_i;
      float share = ov_i * ci + ov_c * c;
      float c_re  = up_i * ci + up_c * c + share;
      float c_ner = dn_i * ci + dn_c * c + share;
      cat_l[tid] = c_re; cat_l[HH + tid] = c_ner; cat_l[2 * HH + tid] = share;
      int sb = ch * OPB;
      if (tid >= sb && tid < sb + OPB) {
        size_t ob = ((size_t)t * BB + b) * HH + tid;
        hner[ob] = tanhf(c_ner); hre[ob] = tanhf(c_re); hsh[ob] = tanhf(share);
      }
    }
    __syncthreads();
    if (tid < 480) {
      float acc = 0.f;
      #pragma unroll
      for (int q = 0; q < 29; ++q)
        if (q < nk2) acc += wt[q].x * cat_l[2 * (k2b + q)] + wt[q].y * cat_l[2 * (k2b + q) + 1];
      ps[tid] = acc;
    }
    __syncthreads();
    if (tid < OPB) {
      float co = btrf[ch * OPB + tid];
      #pragma unroll
      for (int q = 0; q < 16; ++q) co += ps[q * OPB + tid];
      astore(cb + ch * OPB + tid, co);
      astore(hb + ch * OPB + tid, tanhf(co));
    }
    gbar(flags + 2 * t + 1, tid, NCHB);
  }
}

// ---- fused h_glob + A/E features (both tasks, 4 lb-rows per block) ----
__global__ void k_globfeat(const float* hsh, const float* hner, const float* hre,
                           const void* nW, const void* nb, const void* rW, const void* rb,
                           const void* nhW, const void* nhb, const void* rhW, const void* rhb,
                           const void* mk, float* hg0, float* hg1,
                           float* A0, float* E0, float* A1, float* E1) {
  bool f32 = is32(mk);
  int sel = blockIdx.x >> 8;       // 0 = glob, 1 = feat
  int task = (blockIdx.x >> 7) & 1;
  int lb0 = (blockIdx.x & 127) * 4;
  const float* tsk = task ? hre : hner;
  int tid = threadIdx.x;
  if (sel == 0) {
    const void* gWo = task ? rW : nW;
    const void* gbo = task ? rb : nb;
    float* hg = task ? hg1 : hg0;
    __shared__ __align__(16) float catl[2400];
    for (int e = tid; e < 2400; e += 320) {
      int rr = e / 600, c = e - rr * 600;
      catl[e] = (c < HH) ? hsh[(size_t)(lb0 + rr) * HH + c] : tsk[(size_t)(lb0 + rr) * HH + (c - HH)];
    }
    __syncthreads();
    if (tid < HH) {
      float bias = ldin(gbo, tid, f32);
      float acc[4] = {bias, bias, bias, bias};
      if (f32) {
        const float4* row = (const float4*)((const float*)gWo + (size_t)tid * 600);
        #pragma unroll 2
        for (int k = 0; k < 150; ++k) {
          float4 u = row[k];
          #pragma unroll
          for (int rr = 0; rr < 4; ++rr) {
            const float4 cv = *(const float4*)(catl + rr * 600 + 4 * k);
            acc[rr] += u.x * cv.x + u.y * cv.y + u.z * cv.z + u.w * cv.w;
          }
        }
      } else {
        for (int k = 0; k < 600; ++k) {
          float w = ldin(gWo, tid * 600 + k, f32);
          #pragma unroll
          for (int rr = 0; rr < 4; ++rr) acc[rr] += w * catl[rr * 600 + k];
        }
      }
      #pragma unroll
      for (int rr = 0; rr < 4; ++rr) hg[(size_t)(lb0 + rr) * HH + tid] = tanhf(acc[rr]);
    }
  } else {
    const void* hWo = task ? rhW : nhW;
    const void* hbo = task ? rhb : nhb;
    float* A = task ? A1 : A0;
    float* E = task ? E1 : E0;
    __shared__ __align__(16) float tl[1200];
    for (int e = tid; e < 1200; e += 320) {
      int rr = e / 300, c = e - rr * 300;
      tl[e] = tsk[(size_t)(lb0 + rr) * HH + c];
    }
    __syncthreads();
    if (tid < HH) {
      float bias = ldin(hbo, tid, f32);
      float a[4] = {bias, bias, bias, bias};
      float ev[4] = {0.f, 0.f, 0.f, 0.f};
      if (f32) {
        const float4* r1 = (const float4*)((const float*)hWo + (size_t)tid * H3);
        const float4* r2 = (const float4*)((const float*)hWo + (size_t)tid * H3 + HH);
        #pragma unroll 2
        for (int k = 0; k < 75; ++k) {
          float4 u = r1[k], w2 = r2[k];
          #pragma unroll
          for (int rr = 0; rr < 4; ++rr) {
            const float4 tv = *(const float4*)(tl + rr * 300 + 4 * k);
            a[rr]  += u.x * tv.x + u.y * tv.y + u.z * tv.z + u.w * tv.w;
            ev[rr] += w2.x * tv.x + w2.y * tv.y + w2.z * tv.z + w2.w * tv.w;
          }
        }
      } else {
        for (int k = 0; k < HH; ++k) {
          float w1 = ldin(hWo, tid * H3 + k, f32);
          float w2 = ldin(hWo, tid * H3 + HH + k, f32);
          #pragma unroll
          for (int rr = 0; rr < 4; ++rr) {
            a[rr] += w1 * tl[rr * 300 + k];
            ev[rr] += w2 * tl[rr * 300 + k];
          }
        }
      }
      #pragma unroll
      for (int rr = 0; rr < 4; ++rr) {
        A[(size_t)(lb0 + rr) * HH + tid] = a[rr];
        E[(size_t)(lb0 + rr) * HH + tid] = ev[rr];
      }
    }
  }
}

// ---- fused gmax + gf: 8 blocks (task x batch) ----
__global__ void k_gmf(const float* hg0, const float* hg1, const void* nhW, const void* rhW,
                      const void* mk, float* Gf0, float* Gf1) {
  bool f32 = is32(mk);
  int task = blockIdx.x >> 2, b = blockIdx.x & 3;
  const float* hg = task ? hg1 : hg0;
  const void* hWo = task ? rhW : nhW;
  float* Gf = task ? Gf1 : Gf0;
  __shared__ __align__(16) float gl[304];
  int tid = threadIdx.x;
  if (tid < HH) {
    float m = -1e30f;
    for (int l = 0; l < LLEN; ++l) m = fmaxf(m, hg[((size_t)l * BB + b) * HH + tid]);
    gl[tid] = m;
  }
  __syncthreads();
  if (tid < HH) {
    float acc = 0.f;
    if (f32) {
      const float4* row = (const float4*)((const float*)hWo + (size_t)tid * H3 + 600);
      #pragma unroll 5
      for (int k = 0; k < 75; ++k) {
        float4 u = row[k];
        const float4 gv = *(const float4*)(gl + 4 * k);
        acc += u.x * gv.x + u.y * gv.y + u.z * gv.z + u.w * gv.w;
      }
    } else {
      for (int k = 0; k < HH; ++k) acc += gl[k] * ldin(hWo, tid * H3 + 600 + k, f32);
    }
    Gf[b * HH + tid] = acc;
  }
}

// ---- pair epilogue: both tasks in one launch, 8 j-pairs per block ----
__global__ void __launch_bounds__(256) k_pair7(const float* A0, const float* E0, const float* Gf0,
                                               const void* lg0, const void* lb0_, const void* tW0, const void* tb0,
                                               const float* A1, const float* E1, const float* Gf1,
                                               const void* lg1, const void* lb1_, const void* tW1, const void* tb1,
                                               const void* mk, void* outv) {
  __shared__ float lg_l[304], lb_l[304], tb_l[16];
  __shared__ float tw_l[3616];
  bool f32 = is32(mk);
  int tau = blockIdx.x >> 11;
  int bid = blockIdx.x & 2047;
  const float* A  = tau ? A1 : A0;
  const float* E  = tau ? E1 : E0;
  const float* Gf = tau ? Gf1 : Gf0;
  const void* lgo = tau ? lg1 : lg0;
  const void* lbo = tau ? lb1_ : lb0_;
  const void* tWo = tau ? tW1 : tW0;
  const void* tbo = tau ? tb1 : tb0;
  int T = tau ? NRR : NTT;
  int diag = tau ? 0 : 1;
  int Toff = tau ? 458752 : 0;
  int tid = threadIdx.x;
  for (int i2 = tid; i2 < HH; i2 += 256) { lg_l[i2] = ldin(lgo, i2, f32); lb_l[i2] = ldin(lbo, i2, f32); }
  for (int i2 = tid; i2 < T * HH; i2 += 256) tw_l[i2] = ldin(tWo, i2, f32);
  if (tid < T) tb_l[tid] = ldin(tbo, tid, f32);
  __syncthreads();
  int i = bid >> 4;
  int j0 = (bid & 15) << 3;
  int b = tid >> 6, ln = tid & 63;
  const float* ar = A  + (size_t)(i * BB + b) * HH;
  const float* gr = Gf + (size_t)b * HH;
  bool ok4 = ln < 44;
  float a0 = ar[ln]       + gr[ln];
  float a1 = ar[64 + ln]  + gr[64 + ln];
  float a2 = ar[128 + ln] + gr[128 + ln];
  float a3 = ar[192 + ln] + gr[192 + ln];
  float a4 = ok4 ? (ar[256 + ln] + gr[256 + ln]) : 0.f;
  float mi = ldin(mk, i * BB + b, f32);
  for (int dj = 0; dj < 8; ++dj) {
    int jx = j0 + dj;
    const float* er = E + (size_t)(jx * BB + b) * HH;
    float u0 = a0 + er[ln];
    float u1 = a1 + er[64 + ln];
    float u2 = a2 + er[128 + ln];
    float u3 = a3 + er[192 + ln];
    float u4 = ok4 ? (a4 + er[256 + ln]) : 0.f;
    float s1 = ((u0 + u1) + (u2 + u3)) + u4;
    float s2 = ((u0 * u0 + u1 * u1) + (u2 * u2 + u3 * u3)) + u4 * u4;
    #pragma unroll
    for (int d = 1; d < 64; d <<= 1) { s1 += __shfl_xor(s1, d); s2 += __shfl_xor(s2, d); }
    float mean = s1 * (1.f / 300.f);
    float var = s2 * (1.f / 300.f) - mean * mean;
    float rstd = rsqrtf(var + 1e-5f);
    {
      float y;
      y = (u0 - mean) * rstd * lg_l[ln]       + lb_l[ln];       u0 = (y > 0.f) ? y : __expf(y) - 1.f;
      y = (u1 - mean) * rstd * lg_l[64 + ln]  + lb_l[64 + ln];  u1 = (y > 0.f) ? y : __expf(y) - 1.f;
      y = (u2 - mean) * rstd * lg_l[128 + ln] + lb_l[128 + ln]; u2 = (y > 0.f) ? y : __expf(y) - 1.f;
      y = (u3 - mean) * rstd * lg_l[192 + ln] + lb_l[192 + ln]; u3 = (y > 0.f) ? y : __expf(y) - 1.f;
      if (ok4) {
        y = (u4 - mean) * rstd * lg_l[256 + ln] + lb_l[256 + ln];
        u4 = (y > 0.f) ? y : __expf(y) - 1.f;
      }
    }
    float m = mi * ldin(mk, jx * BB + b, f32);
    if (diag && jx < i) m = 0.f;
    size_t obase = (size_t)Toff + ((size_t)(i * LLEN + jx) * BB + b) * T;
    float mine = 0.f;
    for (int t = 0; t < T; ++t) {
      const float* twr = tw_l + t * HH;
      float s = u0 * twr[ln] + u1 * twr[64 + ln] + u2 * twr[128 + ln] + u3 * twr[192 + ln];
      if (ok4) s += u4 * twr[256 + ln];
      s = wsum(s);
      s += tb_l[t];
      float o = m / (1.f + __expf(-s));
      mine = (ln == t) ? o : mine;
    }
    if (ln < T) {
      if (f32) ((float*)outv)[obase + ln] = mine;
      else ((u16*)outv)[obase + ln] = f2bf(mine);
    }
  }
}

// ---- sentinel ----
__global__ void k_sent(const void* mk, const void* xo, void* outv, int hostcode) {
  __shared__ int bad;
  if (threadIdx.x == 0) bad = 0;
  __syncthreads();
  bool f32 = is32(mk);
  for (int i = threadIdx.x; i < 4096; i += 256) {
    float v = ldin(xo, i, f32);
    if (!(v == v) || fabsf(v) > 1e6f) bad = 1;
  }
  __syncthreads();
  if (threadIdx.x == 0) {
    float code = (float)hostcode;
    if (bad) code = fmaxf(code, 88.f);
    if (code > 0.f) {
      if (f32) ((float*)outv)[0] = code;
      else ((u16*)outv)[0] = f2bf(code);
    }
  }
}

extern "C" void kernel_launch(void* const* d_in, const int* in_sizes, int n_in,
                              void* d_out, int out_size, void* d_ws, size_t ws_size,
                              hipStream_t stream) {
  const void* x    = d_in[0];
  const void* mask = d_in[1];
  const void* Wih  = d_in[2];
  const void* bih  = d_in[3];
  const void* Whh  = d_in[4];
  const void* bhh  = d_in[5];
  const void* Wtr  = d_in[6];
  const void* btr  = d_in[7];
  const void* nW   = d_in[8];
  const void* nb   = d_in[9];
  const void* nhW  = d_in[10];
  const void* nhb  = d_in[11];
  const void* ng   = d_in[12];
  const void* nbe  = d_in[13];
  const void* ntW  = d_in[14];
  const void* ntb  = d_in[15];
  const void* rW   = d_in[16];
  const void* rb   = d_in[17];
  const void* rhW  = d_in[18];
  const void* rhb  = d_in[19];
  const void* rg   = d_in[20];
  const void* rbe  = d_in[21];
  const void* rtW  = d_in[22];
  const void* rtb  = d_in[23];
  float* ws = (float*)d_ws;

  static const int exp_sz[24] = {393216, 512, 1152000, 1500, 450000, 1500, 270000, 300,
                                 180000, 300, 270000, 300, 300, 300, 2100, 7,
                                 180000, 300, 270000, 300, 300, 300, 3600, 12};
  int hostcode = 0;
  if (n_in != 24) hostcode = 890;
  else {
    for (int ii = 0; ii < 24; ++ii)
      if (in_sizes[ii] != exp_sz[ii]) { hostcode = 900 + ii; break; }
  }
  if (hostcode == 0 && out_size != 1245184) hostcode = 880;
  if (hostcode == 0 && ws_size < WS_NEED_BYTES) hostcode = 1099;

  dim3 gc(4500, 2);
  k_canon2<<<gc, 256, 0, stream>>>(x, mask, Wih, ws);
  k_misc<<<12, 256, 0, stream>>>(bih, bhh, btr, mask, ws);
  k_pre2<<<128, 256, 0, stream>>>(x, Wih, mask, ws + C_X, ws + C_WIH, ws + F_BIH, ws + F_PRE);
  k_scan5<<<40, 512, 0, stream>>>(ws + F_PRE, Whh, Wtr, mask, ws + F_BTR,
                                  ws + F_HNER, ws + F_HRE, ws + F_HSH, ws + F_AUX);
  k_globfeat<<<512, 320, 0, stream>>>(ws + F_HSH, ws + F_HNER, ws + F_HRE,
                                      nW, nb, rW, rb, nhW, nhb, rhW, rhb, mask,
                                      ws + F_HG0, ws + F_HG1,
                                      ws + F_A0, ws + F_E0, ws + F_A1, ws + F_E1);
  k_gmf<<<8, 320, 0, stream>>>(ws + F_HG0, ws + F_HG1, nhW, rhW, mask, ws + F_GF0, ws + F_GF1);
  k_pair7<<<4096, 256, 0, stream>>>(ws + F_A0, ws + F_E0, ws + F_GF0, ng, nbe, ntW, ntb,
                                    ws + F_A1, ws + F_E1, ws + F_GF1, rg, rbe, rtW, rtb,
                                    mask, d_out);
  k_sent<<<1, 256, 0, stream>>>(mask, x, d_out, hostcode);
}

// Round 16
// 1536.896 us; speedup vs baseline: 1.0426x; 1.0426x over previous
//
#include <hip/hip_runtime.h>

#define LLEN 128
#define BB 4
#define DD 768
#define HH 300
#define G5 1500
#define H3 900
#define NTT 7
#define NRR 12
#define NCHB 10
#define RPB 150
#define OPB 30

// ---- fp32 workspace layout (ws as float*) ----
#define C_WIH  0
#define C_X    1152000
#define C_WHH2 1545216
#define C_WTR2 1995216
#define F_BIH  2265216
#define F_BTR  2266720
#define F_PRE  2267040
// PRE region reused after k_scan4:
#define F_HG0  (F_PRE)
#define F_HG1  (F_PRE+153600)
#define F_A0   (F_PRE+307200)
#define F_E0   (F_PRE+460800)
#define F_GF0  (F_PRE+616832)
#define F_GF1  (F_PRE+618048)
// beyond PRE:
#define F_HNER (F_PRE+768000)
#define F_HRE  (F_HNER+153600)
#define F_HSH  (F_HRE+153600)
// A1/E1 live in the DEAD Wih region (Wih canon only read by k_pre2, which runs before k_feat2)
#define F_A1   0
#define F_E1   153600
#define F_AUX  (F_HSH+153600)
// aux per-batch (AUXB floats): gb[0,1500) cb[1504,1804) hb[1808,2108) sums[2112,2128)
#define AUXB   2432
#define AUX_FL 9728
#define WS_NEED_BYTES ((size_t)(F_AUX+10752)*4)

typedef unsigned short u16;
typedef unsigned int u32;

__device__ __forceinline__ float bf2f(u16 u) {
  union { u32 i; float f; } v; v.i = ((u32)u) << 16; return v.f;
}
__device__ __forceinline__ u16 f2bf(float f) {
  union { float f; u32 i; } v; v.f = f;
  u32 r = v.i + 0x7fffu + ((v.i >> 16) & 1u);
  return (u16)(r >> 16);
}
__device__ __forceinline__ float ldin(const void* p, int i, bool f32) {
  return f32 ? ((const float*)p)[i] : bf2f(((const u16*)p)[i]);
}
__device__ __forceinline__ bool is32(const void* mk) {
  return ((const u16*)mk)[0] == 0;  // fp32 1.0 low half = 0x0000; bf16 1.0 = 0x3F80
}
__device__ __forceinline__ float wsum(float x) {
  #pragma unroll
  for (int d = 1; d < 64; d <<= 1) x += __shfl_xor(x, d);
  return x;
}
// coherent (agent-scope, sc1) handoff accessors
__device__ __forceinline__ float aload(const float* p) {
  int v = __hip_atomic_load((const int*)p, __ATOMIC_RELAXED, __HIP_MEMORY_SCOPE_AGENT);
  union { int i; float f; } u; u.i = v; return u.f;
}
__device__ __forceinline__ void astore(float* p, float v) {
  union { float f; int i; } u; u.f = v;
  __hip_atomic_store((int*)p, u.i, __ATOMIC_RELAXED, __HIP_MEMORY_SCOPE_AGENT);
}
// lean inter-block barrier (R12/R13/R14-proven)
__device__ __forceinline__ void gbar(int* flag, int tid, int target) {
  __syncthreads();
  if (tid == 0) {
    __builtin_amdgcn_s_waitcnt(0);
    __hip_atomic_fetch_add(flag, 1, __ATOMIC_RELAXED, __HIP_MEMORY_SCOPE_AGENT);
    while (__hip_atomic_load(flag, __ATOMIC_RELAXED, __HIP_MEMORY_SCOPE_AGENT) < target)
      __builtin_amdgcn_s_sleep(1);
  }
  __syncthreads();
}

// ---- canonicalize: (bf16 path: fp32 X/Wih), packed Whh/Wtr, biases, flag zero ----
__global__ void k_canon(const void* xo, const void* mk, const void* Wih, const void* bih,
                        const void* Whh, const void* bhh, const void* Wtr, const void* btr,
                        float* ws) {
  bool f32 = is32(mk);
  int piece = blockIdx.y;
  int i = blockIdx.x * 256 + threadIdx.x;
  switch (piece) {
    case 0: if (!f32 && i < 1152000) ws[C_WIH + i] = ldin(Wih, i, f32); break;
    case 1: if (!f32 && i < 393216)  ws[C_X + i]   = ldin(xo, i, f32);  break;
    case 2: if (i < 225000) {  // W2hh[k2][out] as float2, k2<150, out<1500
      int k2 = i / G5, out = i - k2 * G5;
      float2 v;
      v.x = ldin(Whh, out * HH + 2 * k2, f32);
      v.y = ldin(Whh, out * HH + 2 * k2 + 1, f32);
      ((float2*)(ws + C_WHH2))[i] = v;
    } break;
    case 3: if (i < 135000) {  // W2tr[k2][out] as float2, k2<450, out<300
      int k2 = i / HH, out = i - k2 * HH;
      float2 v;
      v.x = ldin(Wtr, out * H3 + 2 * k2, f32);
      v.y = ldin(Wtr, out * H3 + 2 * k2 + 1, f32);
      ((float2*)(ws + C_WTR2))[i] = v;
    } break;
    case 4: {
      if (i < 1504) ws[F_BIH + i] = (i < G5) ? ldin(bih, i, f32) + ldin(bhh, i, f32) : 0.f;
      else if (i < 1824) { int j = i - 1504; ws[F_BTR + j] = (j < HH) ? ldin(btr, j, f32) : 0.f; }
    } break;
    case 5: if (i < 1024) ((int*)(ws + F_AUX + AUX_FL))[i] = 0; break;
  }
}

// ---- pre = x @ W_ih^T + (b_ih + b_hh); 8 lb-rows x 750-out tile per block ----
__global__ void k_pre2(const void* xo, const void* Wo, const void* mk,
                       const float* cX, const float* cW, const float* biasf, float* pre) {
  bool f32 = is32(mk);
  const float* X = f32 ? (const float*)xo : cX;
  const float* W = f32 ? (const float*)Wo : cW;
  __shared__ __align__(16) float xl[8 * DD];
  int tid = threadIdx.x;
  int lb0 = (blockIdx.x >> 1) * 8;
  int half = blockIdx.x & 1;
  for (int e = tid; e < 8 * DD; e += 256) xl[e] = X[(size_t)lb0 * DD + e];
  __syncthreads();
  for (int j = half * 750 + tid; j < half * 750 + 750; j += 256) {
    const float4* w = (const float4*)(W + (size_t)j * DD);
    float acc[8] = {0.f, 0.f, 0.f, 0.f, 0.f, 0.f, 0.f, 0.f};
    #pragma unroll 2
    for (int k = 0; k < DD / 4; ++k) {
      float4 u = w[k];
      #pragma unroll
      for (int r = 0; r < 8; ++r) {
        const float4 p = *(const float4*)(xl + r * DD + k * 4);
        acc[r] += u.x * p.x + u.y * p.y + u.z * p.z + u.w * p.w;
      }
    }
    float bias = biasf[j];
    #pragma unroll
    for (int r = 0; r < 8; ++r) pre[(size_t)(lb0 + r) * G5 + j] = acc[r] + bias;
  }
}

// ---- scan: 10 chunk-blocks x 4 batches; REGISTER-RESIDENT weights (R13/R14-proven) ----
__global__ void __launch_bounds__(512, 2) k_scan4(const float* pre, const float2* W2h, const float2* W2t,
                                                  const float* btrf, float* hner, float* hre, float* hsh,
                                                  float* aux) {
  __shared__ __align__(16) float h_l[304];
  __shared__ __align__(16) float ci_l[304];
  __shared__ __align__(16) float ga_l[1504];
  __shared__ __align__(16) float cat_l[904];
  __shared__ __align__(16) float ps[512];
  __shared__ float exv[160];
  __shared__ float pp[40];
  __shared__ float sums_l[8];
  int b = blockIdx.x / NCHB, ch = blockIdx.x % NCHB;
  int s = ch >> 1;
  int r0 = ch * RPB;
  int tid = threadIdx.x;
  float* gb   = aux + b * AUXB;
  float* cb   = gb + 1504;
  float* hb   = gb + 1808;
  float* sums = gb + 2112;
  int* flags = (int*)(aux + AUX_FL) + b * 256;
  for (int i = tid; i < 304; i += 512) { h_l[i] = 0.f; ci_l[i] = 0.f; }
  __syncthreads();
  int j = tid / RPB, r = tid - j * RPB;
  int o2 = tid % OPB, jj = tid / OPB;
  int kb = j * 100;

  float2 wh[50];
  if (tid < 450) {
    const float2* wp = W2h + (size_t)(j * 50) * G5 + (r0 + r);
    #pragma unroll
    for (int kk = 0; kk < 50; ++kk) wh[kk] = wp[(size_t)kk * G5];
  }
  float2 wt[29];
  int k2b = jj * 29;
  int k2e = (k2b + 29 < 450) ? (k2b + 29) : 450;
  int nk2 = k2e - k2b;
  if (tid < 480) {
    const float2* wp = W2t + (size_t)k2b * HH + (ch * OPB + o2);
    #pragma unroll
    for (int q = 0; q < 29; ++q) if (q < nk2) wt[q] = wp[(size_t)q * HH];
  }

  for (int t = 0; t < LLEN; ++t) {
    if (t > 0) {
      for (int i = tid; i < HH; i += 512) { h_l[i] = aload(hb + i); ci_l[i] = aload(cb + i); }
      __syncthreads();
    }
    if (tid < 450) {
      float acc = (j == 0) ? pre[((size_t)t * BB + b) * G5 + r0 + r] : 0.f;
      if (t > 0) {
        #pragma unroll
        for (int kk = 0; kk < 50; ++kk)
          acc += wh[kk].x * h_l[kb + 2 * kk] + wh[kk].y * h_l[kb + 2 * kk + 1];
      }
      ps[tid] = acc;
    }
    __syncthreads();
    if (tid < RPB) {
      float g = ps[tid] + ps[RPB + tid] + ps[2 * RPB + tid];
      if (s == 0) astore(gb + r0 + tid, tanhf(g));
      else exv[tid] = __expf(g);
    }
    __syncthreads();
    if (s > 0) {
      if (tid < 30) {
        int base = tid * 5;
        pp[tid] = ((exv[base] + exv[base+1]) + (exv[base+2] + exv[base+3])) + exv[base+4];
      }
      __syncthreads();
      if (tid == 0) {
        float run = 0.f;
        for (int i = 0; i < 30; ++i) { float tv = pp[i]; pp[i] = run; run += tv; }
        astore(sums + (ch - 2), run);
      }
      __syncthreads();
      if (tid < 30) {
        int base = tid * 5;
        float run = pp[tid];
        run += exv[base];     astore(gb + r0 + base,     run);
        run += exv[base + 1]; astore(gb + r0 + base + 1, run);
        run += exv[base + 2]; astore(gb + r0 + base + 2, run);
        run += exv[base + 3]; astore(gb + r0 + base + 3, run);
        run += exv[base + 4]; astore(gb + r0 + base + 4, run);
      }
    }
    gbar(flags + 2 * t, tid, NCHB);
    for (int i = tid; i < G5; i += 512) ga_l[i] = aload(gb + i);
    if (tid < 8) sums_l[tid] = aload(sums + tid);
    __syncthreads();
    if (tid < HH) {
      float c = ga_l[tid];
      float v[4];
      #pragma unroll
      for (int s1 = 0; s1 < 4; ++s1) {
        float raw = ga_l[(s1 + 1) * HH + tid];
        float off = (tid >= RPB) ? sums_l[2 * s1] : 0.f;
        float S = sums_l[2 * s1] + sums_l[2 * s1 + 1];
        v[s1] = (raw + off) / S;
      }
      float eg_cin = 1.f - v[0], rg_cin = v[1], eg_c = 1.f - v[2], rg_c = v[3];
      float ci = (t > 0) ? ci_l[tid] : 0.f;
      float ov_c = rg_c * eg_c;
      float up_c = rg_c - ov_c, dn_c = eg_c - ov_c;
      float ov_i = rg_cin * eg_cin;
      float up_i = rg_cin - ov_i, dn_i = eg_cin - ov_i;
      float share = ov_i * ci + ov_c * c;
      float c_re  = up_i * ci + up_c * c + share;
      float c_ner = dn_i * ci + dn_c * c + share;
      cat_l[tid] = c_re; cat_l[HH + tid] = c_ner; cat_l[2 * HH + tid] = share;
      int sb = ch * OPB;
      if (tid >= sb && tid < sb + OPB) {
        size_t ob = ((size_t)t * BB + b) * HH + tid;
        hner[ob] = tanhf(c_ner); hre[ob] = tanhf(c_re); hsh[ob] = tanhf(share);
      }
    }
    __syncthreads();
    if (tid < 480) {
      float acc = 0.f;
      #pragma unroll
      for (int q = 0; q < 29; ++q)
        if (q < nk2) acc += wt[q].x * cat_l[2 * (k2b + q)] + wt[q].y * cat_l[2 * (k2b + q) + 1];
      ps[tid] = acc;
    }
    __syncthreads();
    if (tid < OPB) {
      float co = btrf[ch * OPB + tid];
      #pragma unroll
      for (int q = 0; q < 16; ++q) co += ps[q * OPB + tid];
      astore(cb + ch * OPB + tid, co);
      astore(hb + ch * OPB + tid, tanhf(co));
    }
    gbar(flags + 2 * t + 1, tid, NCHB);
  }
}

// ---- h_glob: both tasks, 4 lb-rows per block ----
__global__ void k_glob3(const float* hsh, const float* hner, const float* hre,
                        const void* nW, const void* nb, const void* rW, const void* rb,
                        const void* mk, float* hg0, float* hg1) {
  bool f32 = is32(mk);
  int task = blockIdx.x >> 7;
  int lb0 = (blockIdx.x & 127) * 4;
  const float* tsk = task ? hre : hner;
  const void* gWo = task ? rW : nW;
  const void* gbo = task ? rb : nb;
  float* hg = task ? hg1 : hg0;
  __shared__ __align__(16) float catl[2400];
  int tid = threadIdx.x;
  for (int e = tid; e < 2400; e += 320) {
    int rr = e / 600, c = e - rr * 600;
    catl[e] = (c < HH) ? hsh[(size_t)(lb0 + rr) * HH + c] : tsk[(size_t)(lb0 + rr) * HH + (c - HH)];
  }
  __syncthreads();
  if (tid < HH) {
    float bias = ldin(gbo, tid, f32);
    float acc[4] = {bias, bias, bias, bias};
    if (f32) {
      const float4* row = (const float4*)((const float*)gWo + (size_t)tid * 600);
      #pragma unroll 2
      for (int k = 0; k < 150; ++k) {
        float4 u = row[k];
        #pragma unroll
        for (int rr = 0; rr < 4; ++rr) {
          const float4 cv = *(const float4*)(catl + rr * 600 + 4 * k);
          acc[rr] += u.x * cv.x + u.y * cv.y + u.z * cv.z + u.w * cv.w;
        }
      }
    } else {
      for (int k = 0; k < 600; ++k) {
        float w = ldin(gWo, tid * 600 + k, f32);
        #pragma unroll
        for (int rr = 0; rr < 4; ++rr) acc[rr] += w * catl[rr * 600 + k];
      }
    }
    #pragma unroll
    for (int rr = 0; rr < 4; ++rr) hg[(size_t)(lb0 + rr) * HH + tid] = tanhf(acc[rr]);
  }
}

// ---- A/E features: both tasks, 4 lb-rows per block ----
__global__ void k_feat2(const float* hner, const float* hre,
                        const void* nhW, const void* nhb, const void* rhW, const void* rhb,
                        const void* mk, float* A0, float* E0, float* A1, float* E1) {
  bool f32 = is32(mk);
  int task = blockIdx.x >> 7;
  int lb0 = (blockIdx.x & 127) * 4;
  const float* tsk = task ? hre : hner;
  const void* hWo = task ? rhW : nhW;
  const void* hbo = task ? rhb : nhb;
  float* A = task ? A1 : A0;
  float* E = task ? E1 : E0;
  __shared__ __align__(16) float tl[1200];
  int tid = threadIdx.x;
  for (int e = tid; e < 1200; e += 320) {
    int rr = e / 300, c = e - rr * 300;
    tl[e] = tsk[(size_t)(lb0 + rr) * HH + c];
  }
  __syncthreads();
  if (tid < HH) {
    float bias = ldin(hbo, tid, f32);
    float a[4] = {bias, bias, bias, bias};
    float ev[4] = {0.f, 0.f, 0.f, 0.f};
    if (f32) {
      const float4* r1 = (const float4*)((const float*)hWo + (size_t)tid * H3);
      const float4* r2 = (const float4*)((const float*)hWo + (size_t)tid * H3 + HH);
      #pragma unroll 2
      for (int k = 0; k < 75; ++k) {
        float4 u = r1[k], w2 = r2[k];
        #pragma unroll
        for (int rr = 0; rr < 4; ++rr) {
          const float4 tv = *(const float4*)(tl + rr * 300 + 4 * k);
          a[rr]  += u.x * tv.x + u.y * tv.y + u.z * tv.z + u.w * tv.w;
          ev[rr] += w2.x * tv.x + w2.y * tv.y + w2.z * tv.z + w2.w * tv.w;
        }
      }
    } else {
      for (int k = 0; k < HH; ++k) {
        float w1 = ldin(hWo, tid * H3 + k, f32);
        float w2 = ldin(hWo, tid * H3 + HH + k, f32);
        #pragma unroll
        for (int rr = 0; rr < 4; ++rr) {
          a[rr] += w1 * tl[rr * 300 + k];
          ev[rr] += w2 * tl[rr * 300 + k];
        }
      }
    }
    #pragma unroll
    for (int rr = 0; rr < 4; ++rr) {
      A[(size_t)(lb0 + rr) * HH + tid] = a[rr];
      E[(size_t)(lb0 + rr) * HH + tid] = ev[rr];
    }
  }
}

// ---- fused gmax + gf: 8 blocks (task x batch) ----
__global__ void k_gmf(const float* hg0, const float* hg1, const void* nhW, const void* rhW,
                      const void* mk, float* Gf0, float* Gf1) {
  bool f32 = is32(mk);
  int task = blockIdx.x >> 2, b = blockIdx.x & 3;
  const float* hg = task ? hg1 : hg0;
  const void* hWo = task ? rhW : nhW;
  float* Gf = task ? Gf1 : Gf0;
  __shared__ __align__(16) float gl[304];
  int tid = threadIdx.x;
  if (tid < HH) {
    float m = -1e30f;
    for (int l = 0; l < LLEN; ++l) m = fmaxf(m, hg[((size_t)l * BB + b) * HH + tid]);
    gl[tid] = m;
  }
  __syncthreads();
  if (tid < HH) {
    float acc = 0.f;
    if (f32) {
      const float4* row = (const float4*)((const float*)hWo + (size_t)tid * H3 + 600);
      #pragma unroll 5
      for (int k = 0; k < 75; ++k) {
        float4 u = row[k];
        const float4 gv = *(const float4*)(gl + 4 * k);
        acc += u.x * gv.x + u.y * gv.y + u.z * gv.z + u.w * gv.w;
      }
    } else {
      for (int k = 0; k < HH; ++k) acc += gl[k] * ldin(hWo, tid * H3 + 600 + k, f32);
    }
    Gf[b * HH + tid] = acc;
  }
}

// ---- pair epilogue: both tasks in one launch, 4 j-pairs per block ----
__global__ void __launch_bounds__(256) k_pair6(const float* A0, const float* E0, const float* Gf0,
                                               const void* lg0, const void* lb0_, const void* tW0, const void* tb0,
                                               const float* A1, const float* E1, const float* Gf1,
                                               const void* lg1, const void* lb1_, const void* tW1, const void* tb1,
                                               const void* mk, void* outv) {
  __shared__ float lg_l[304], lb_l[304], tb_l[16];
  __shared__ float tw_l[3616];
  bool f32 = is32(mk);
  int tau = blockIdx.x >> 12;
  int bid = blockIdx.x & 4095;
  const float* A  = tau ? A1 : A0;
  const float* E  = tau ? E1 : E0;
  const float* Gf = tau ? Gf1 : Gf0;
  const void* lgo = tau ? lg1 : lg0;
  const void* lbo = tau ? lb1_ : lb0_;
  const void* tWo = tau ? tW1 : tW0;
  const void* tbo = tau ? tb1 : tb0;
  int T = tau ? NRR : NTT;
  int diag = tau ? 0 : 1;
  int Toff = tau ? 458752 : 0;
  int tid = threadIdx.x;
  for (int i2 = tid; i2 < HH; i2 += 256) { lg_l[i2] = ldin(lgo, i2, f32); lb_l[i2] = ldin(lbo, i2, f32); }
  for (int i2 = tid; i2 < T * HH; i2 += 256) tw_l[i2] = ldin(tWo, i2, f32);
  if (tid < T) tb_l[tid] = ldin(tbo, tid, f32);
  __syncthreads();
  int i = bid >> 5;
  int j0 = (bid & 31) << 2;
  int b = tid >> 6, ln = tid & 63;
  const float* ar = A  + (size_t)(i * BB + b) * HH;
  const float* gr = Gf + (size_t)b * HH;
  bool ok4 = ln < 44;
  float a0 = ar[ln]       + gr[ln];
  float a1 = ar[64 + ln]  + gr[64 + ln];
  float a2 = ar[128 + ln] + gr[128 + ln];
  float a3 = ar[192 + ln] + gr[192 + ln];
  float a4 = ok4 ? (ar[256 + ln] + gr[256 + ln]) : 0.f;
  float mi = ldin(mk, i * BB + b, f32);
  for (int dj = 0; dj < 4; ++dj) {
    int jx = j0 + dj;
    const float* er = E + (size_t)(jx * BB + b) * HH;
    float u0 = a0 + er[ln];
    float u1 = a1 + er[64 + ln];
    float u2 = a2 + er[128 + ln];
    float u3 = a3 + er[192 + ln];
    float u4 = ok4 ? (a4 + er[256 + ln]) : 0.f;
    float s1 = ((u0 + u1) + (u2 + u3)) + u4;
    float s2 = ((u0 * u0 + u1 * u1) + (u2 * u2 + u3 * u3)) + u4 * u4;
    #pragma unroll
    for (int d = 1; d < 64; d <<= 1) { s1 += __shfl_xor(s1, d); s2 += __shfl_xor(s2, d); }
    float mean = s1 * (1.f / 300.f);
    float var = s2 * (1.f / 300.f) - mean * mean;
    float rstd = rsqrtf(var + 1e-5f);
    {
      float y;
      y = (u0 - mean) * rstd * lg_l[ln]       + lb_l[ln];       u0 = (y > 0.f) ? y : __expf(y) - 1.f;
      y = (u1 - mean) * rstd * lg_l[64 + ln]  + lb_l[64 + ln];  u1 = (y > 0.f) ? y : __expf(y) - 1.f;
      y = (u2 - mean) * rstd * lg_l[128 + ln] + lb_l[128 + ln]; u2 = (y > 0.f) ? y : __expf(y) - 1.f;
      y = (u3 - mean) * rstd * lg_l[192 + ln] + lb_l[192 + ln]; u3 = (y > 0.f) ? y : __expf(y) - 1.f;
      if (ok4) {
        y = (u4 - mean) * rstd * lg_l[256 + ln] + lb_l[256 + ln];
        u4 = (y > 0.f) ? y : __expf(y) - 1.f;
      }
    }
    float m = mi * ldin(mk, jx * BB + b, f32);
    if (diag && jx < i) m = 0.f;
    size_t obase = (size_t)Toff + ((size_t)(i * LLEN + jx) * BB + b) * T;
    float mine = 0.f;
    for (int t = 0; t < T; ++t) {
      const float* twr = tw_l + t * HH;
      float s = u0 * twr[ln] + u1 * twr[64 + ln] + u2 * twr[128 + ln] + u3 * twr[192 + ln];
      if (ok4) s += u4 * twr[256 + ln];
      s = wsum(s);
      s += tb_l[t];
      float o = m / (1.f + __expf(-s));
      mine = (ln == t) ? o : mine;
    }
    if (ln < T) {
      if (f32) ((float*)outv)[obase + ln] = mine;
      else ((u16*)outv)[obase + ln] = f2bf(mine);
    }
  }
}

// ---- sentinel ----
__global__ void k_sent(const void* mk, const void* xo, void* outv, int hostcode) {
  __shared__ int bad;
  if (threadIdx.x == 0) bad = 0;
  __syncthreads();
  bool f32 = is32(mk);
  for (int i = threadIdx.x; i < 4096; i += 256) {
    float v = ldin(xo, i, f32);
    if (!(v == v) || fabsf(v) > 1e6f) bad = 1;
  }
  __syncthreads();
  if (threadIdx.x == 0) {
    float code = (float)hostcode;
    if (bad) code = fmaxf(code, 88.f);
    if (code > 0.f) {
      if (f32) ((float*)outv)[0] = code;
      else ((u16*)outv)[0] = f2bf(code);
    }
  }
}

extern "C" void kernel_launch(void* const* d_in, const int* in_sizes, int n_in,
                              void* d_out, int out_size, void* d_ws, size_t ws_size,
                              hipStream_t stream) {
  const void* x    = d_in[0];
  const void* mask = d_in[1];
  const void* Wih  = d_in[2];
  const void* bih  = d_in[3];
  const void* Whh  = d_in[4];
  const void* bhh  = d_in[5];
  const void* Wtr  = d_in[6];
  const void* btr  = d_in[7];
  const void* nW   = d_in[8];
  const void* nb   = d_in[9];
  const void* nhW  = d_in[10];
  const void* nhb  = d_in[11];
  const void* ng   = d_in[12];
  const void* nbe  = d_in[13];
  const void* ntW  = d_in[14];
  const void* ntb  = d_in[15];
  const void* rW   = d_in[16];
  const void* rb   = d_in[17];
  const void* rhW  = d_in[18];
  const void* rhb  = d_in[19];
  const void* rg   = d_in[20];
  const void* rbe  = d_in[21];
  const void* rtW  = d_in[22];
  const void* rtb  = d_in[23];
  float* ws = (float*)d_ws;

  static const int exp_sz[24] = {393216, 512, 1152000, 1500, 450000, 1500, 270000, 300,
                                 180000, 300, 270000, 300, 300, 300, 2100, 7,
                                 180000, 300, 270000, 300, 300, 300, 3600, 12};
  int hostcode = 0;
  if (n_in != 24) hostcode = 890;
  else {
    for (int ii = 0; ii < 24; ++ii)
      if (in_sizes[ii] != exp_sz[ii]) { hostcode = 900 + ii; break; }
  }
  if (hostcode == 0 && out_size != 1245184) hostcode = 880;
  if (hostcode == 0 && ws_size < WS_NEED_BYTES) hostcode = 1099;

  dim3 gc(4500, 6);
  k_canon<<<gc, 256, 0, stream>>>(x, mask, Wih, bih, Whh, bhh, Wtr, btr, ws);
  k_pre2<<<128, 256, 0, stream>>>(x, Wih, mask, ws + C_X, ws + C_WIH, ws + F_BIH, ws + F_PRE);
  k_scan4<<<40, 512, 0, stream>>>(ws + F_PRE, (const float2*)(ws + C_WHH2), (const float2*)(ws + C_WTR2),
                                  ws + F_BIH + 1504 - 1504 + (F_BTR - F_BIH), ws + F_HNER, ws + F_HRE, ws + F_HSH, ws + F_AUX);
  k_glob3<<<256, 320, 0, stream>>>(ws + F_HSH, ws + F_HNER, ws + F_HRE,
                                   nW, nb, rW, rb, mask, ws + F_HG0, ws + F_HG1);
  k_feat2<<<256, 320, 0, stream>>>(ws + F_HNER, ws + F_HRE, nhW, nhb, rhW, rhb, mask,
                                   ws + F_A0, ws + F_E0, ws + F_A1, ws + F_E1);
  k_gmf<<<8, 320, 0, stream>>>(ws + F_HG0, ws + F_HG1, nhW, rhW, mask, ws + F_GF0, ws + F_GF1);
  k_pair6<<<8192, 256, 0, stream>>>(ws + F_A0, ws + F_E0, ws + F_GF0, ng, nbe, ntW, ntb,
                                    ws + F_A1, ws + F_E1, ws + F_GF1, rg, rbe, rtW, rtb,
                                    mask, d_out);
  k_sent<<<1, 256, 0, stream>>>(mask, x, d_out, hostcode);
}